// Round 5
// baseline (233.817 us; speedup 1.0000x reference)
//
#include <hip/hip_runtime.h>
#include <hip/hip_bf16.h>

#define NN 8192
#define NHEADS 4
#define OUTF 64
#define NCHUNK 4
#define CHUNK 2048
#define ROWS 64
#define LOG2E 1.4426950408889634f

typedef __bf16 bf16x8 __attribute__((ext_vector_type(8)));
typedef float fx4 __attribute__((ext_vector_type(4)));
typedef unsigned short ushort8 __attribute__((ext_vector_type(8)));

// ---------------------------------------------------------------------------
// Kernel 1: Wh = h @ W[hd] (fp32). Outputs (log2-domain factorization):
//   R [hd][i] = 2^(-0.8*es_i*log2e)   (= exp(-0.8*es))
//   F1[hd][j] = 2^(ed_j*log2e),  F2[hd][j] = 2^(0.2*ed_j*log2e)
//   whsw: bf16 Wh^T pre-swizzled into MFMA-16x16x32 B-fragment order.
// Row-factor E1 cancels in softmax normalization, so it is never computed.
// ---------------------------------------------------------------------------
__global__ __launch_bounds__(256) void k_wh(
    const float* __restrict__ h, const float* __restrict__ W,
    const float* __restrict__ a1, const float* __restrict__ a2,
    unsigned short* __restrict__ whsw, float* __restrict__ R,
    float* __restrict__ F1, float* __restrict__ F2)
{
  __shared__ float ws[64 * 260];  // W[hd] transposed: ws[o*260 + k]
  const int tid = threadIdx.x;
  const int hd = blockIdx.x >> 7;
  const int i0 = (blockIdx.x & 127) << 6;   // 64 rows per block

  const float* Wp = W + hd * (256 * 64);
  for (int idx = tid; idx < 256 * 64; idx += 256) {
    int k = idx >> 6, o = idx & 63;
    ws[o * 260 + k] = Wp[idx];
  }
  __syncthreads();

  const int w = tid >> 6, o = tid & 63;     // wave w: rows ibase..+15, col o
  const int ibase = i0 + w * 16;
  float acc[16];
#pragma unroll
  for (int m = 0; m < 16; ++m) acc[m] = 0.f;

  const float* hp = h + (size_t)ibase * 256;
  for (int k4 = 0; k4 < 64; ++k4) {
    fx4 wv = *(const fx4*)(&ws[o * 260 + k4 * 4]);
#pragma unroll
    for (int m = 0; m < 16; ++m) {
      fx4 hv = *(const fx4*)(hp + m * 256 + k4 * 4);
      acc[m] += hv[0] * wv[0] + hv[1] * wv[1] + hv[2] * wv[2] + hv[3] * wv[3];
    }
  }

  const float a1v = a1[hd * 64 + o], a2v = a2[hd * 64 + o];
#pragma unroll
  for (int m = 0; m < 16; ++m) {
    float s1 = acc[m] * a1v, s2 = acc[m] * a2v;
#pragma unroll
    for (int d = 1; d < 64; d <<= 1) {
      s1 += __shfl_xor(s1, d);
      s2 += __shfl_xor(s2, d);
    }
    if (o == 0) {
      int ix = hd * NN + ibase + m;
      R[ix]  = __builtin_amdgcn_exp2f(-0.8f * s1 * LOG2E);
      F1[ix] = __builtin_amdgcn_exp2f(s2 * LOG2E);
      F2[ix] = __builtin_amdgcn_exp2f(0.2f * s2 * LOG2E);
    }
  }

  // swizzled bf16 store of Wh (rows ibase..+15, col o)
  size_t base = (size_t)hd * 524288 + (size_t)((i0 >> 5) + (w >> 1)) * 2048 +
                (size_t)(o >> 4) * 512;
  int ln0 = (o & 15) + 16 * ((w & 1) * 2);
  ushort8 pk0, pk1;
#pragma unroll
  for (int m = 0; m < 8; ++m) {
    pk0[m] = __builtin_bit_cast(unsigned short, (__bf16)acc[m]);
    pk1[m] = __builtin_bit_cast(unsigned short, (__bf16)acc[m + 8]);
  }
  *(ushort8*)(whsw + base + (size_t)ln0 * 8) = pk0;
  *(ushort8*)(whsw + base + (size_t)(ln0 + 16) * 8) = pk1;
}

// ---------------------------------------------------------------------------
// Kernel 2: fused adj->bitmask (LDS) + masked unnormalized softmax + PV MFMA.
// Grid: 512 blocks = 128 row-tiles (64 rows) x 4 j-chunks (2048).
// XCD pinning: blockIdx%8 = XCD (round-robin dispatch); ci = (bx&7)>>1 so
// each XCD touches ONE whsw chunk slice (2 MB, stays L2-resident).
// 4 waves = 4 heads; each wave covers 4 row-sets of 16 rows sharing
// B-fragments/F/masks. q = max(F1_j, r_i*F2_j) masked; rowsum via a 5th
// MFMA against all-ones B.
// ---------------------------------------------------------------------------
struct Tile {
  fx4 f1a, f1b, f2a, f2b;   // F1/F2 slices (per lane group g)
  bf16x8 b0, b1, b2, b3;    // Wh^T B-fragments
  unsigned m[4];            // bitmask words for rowsets 0..3
};

__device__ __forceinline__ void load_tile(Tile& t, const float* F1p,
                                          const float* F2p,
                                          const unsigned short* wp,
                                          const unsigned* bm, int il, int jb)
{
  t.f1a = *(const fx4*)(F1p + jb);
  t.f1b = *(const fx4*)(F1p + jb + 4);
  t.f2a = *(const fx4*)(F2p + jb);
  t.f2b = *(const fx4*)(F2p + jb + 4);
  const unsigned short* wq = wp + (size_t)(jb >> 5) * 2048;
  t.b0 = *(const bf16x8*)(wq);
  t.b1 = *(const bf16x8*)(wq + 512);
  t.b2 = *(const bf16x8*)(wq + 1024);
  t.b3 = *(const bf16x8*)(wq + 1536);
  const unsigned* mb = bm + (jb >> 5) * ROWS;
#pragma unroll
  for (int rs = 0; rs < 4; ++rs) t.m[rs] = mb[rs * 16 + il];
}

__device__ __forceinline__ void compute_tile(const Tile& t, const float* Rr,
                                             int g, const bf16x8& ones,
                                             fx4 acc[4][4], fx4* accS)
{
#pragma unroll
  for (int rs = 0; rs < 4; ++rs) {
    unsigned sm = t.m[rs] >> (g * 8);
    float p[8];
#pragma unroll
    for (int e = 0; e < 8; ++e) {
      float f1 = (e < 4) ? t.f1a[e] : t.f1b[e - 4];
      float f2 = (e < 4) ? t.f2a[e] : t.f2b[e - 4];
      float pm = fmaxf(f1, Rr[rs] * f2);   // ∝ exp(leakyrelu(es+ed))
      unsigned keep = (unsigned)(((int)(sm << (31 - e))) >> 31);
      p[e] = __builtin_bit_cast(float,
                 __builtin_bit_cast(unsigned, pm) & keep);
    }
    bf16x8 af;
#pragma unroll
    for (int e = 0; e < 8; ++e) af[e] = (__bf16)p[e];
    acc[rs][0] = __builtin_amdgcn_mfma_f32_16x16x32_bf16(af, t.b0, acc[rs][0], 0, 0, 0);
    acc[rs][1] = __builtin_amdgcn_mfma_f32_16x16x32_bf16(af, t.b1, acc[rs][1], 0, 0, 0);
    acc[rs][2] = __builtin_amdgcn_mfma_f32_16x16x32_bf16(af, t.b2, acc[rs][2], 0, 0, 0);
    acc[rs][3] = __builtin_amdgcn_mfma_f32_16x16x32_bf16(af, t.b3, acc[rs][3], 0, 0, 0);
    accS[rs] = __builtin_amdgcn_mfma_f32_16x16x32_bf16(af, ones, accS[rs], 0, 0, 0);
  }
}

__global__ __launch_bounds__(256) void k_attn(
    const int* __restrict__ adj, const unsigned short* __restrict__ whsw,
    const float* __restrict__ Rg, const float* __restrict__ F1g,
    const float* __restrict__ F2g, float* __restrict__ pacc,
    float* __restrict__ psum)
{
  __shared__ unsigned bm[(CHUNK / 32) * ROWS];   // [seg32][row] : 16 KiB
  const int tid = threadIdx.x;
  const int lane = tid & 63;
  const int hd = tid >> 6;                 // wave = head
  const int bx = blockIdx.x;
  const int xcd = bx & 7;
  const int ci = xcd >> 1;                 // chunk pinned to XCD pair
  const int rt = ((bx >> 3) << 1) | (xcd & 1);
  const int i0 = rt << 6;                  // 64 rows
  const int j0 = ci * CHUNK;
  const int il = lane & 15;
  const int g = lane >> 4;

  // ---- phase 1: adj region -> LDS bitmask (adj read exactly once) ----
  {
    for (int it = 0; it < 16; ++it) {
      int tb = hd * 512 + it * 32;         // 2048 ballots total
#pragma unroll 4
      for (int blk = 0; blk < 4; ++blk) {
        int v[8];
#pragma unroll
        for (int u = 0; u < 8; ++u) {
          int t = tb + blk * 8 + u;
          int row = t >> 5, sg = t & 31;
          v[u] = adj[(size_t)(i0 + row) * NN + j0 + sg * 64 + lane];
        }
#pragma unroll
        for (int u = 0; u < 8; ++u) {
          int t = tb + blk * 8 + u;
          int row = t >> 5, sg = t & 31;
          unsigned long long m = __ballot(v[u] != 0);
          unsigned word = (lane == 1) ? (unsigned)(m >> 32) : (unsigned)m;
          if (lane < 2) bm[(sg * 2 + lane) * ROWS + row] = word;
        }
      }
    }
  }
  __syncthreads();

  // ---- phase 2: masked softmax + PV ----
  float Rr[4];
#pragma unroll
  for (int rs = 0; rs < 4; ++rs)
    Rr[rs] = Rg[hd * NN + i0 + rs * 16 + il];
  const float* F1p = F1g + hd * NN + j0 + g * 8;
  const float* F2p = F2g + hd * NN + j0 + g * 8;
  const unsigned short* wp = whsw + (size_t)hd * 524288 +
                             (size_t)(j0 >> 5) * 2048 + (size_t)lane * 8;
  bf16x8 ones;
#pragma unroll
  for (int e = 0; e < 8; ++e) ones[e] = (__bf16)1.0f;

  fx4 acc[4][4] = {};
  fx4 accS[4] = {};

  Tile t0, t1;
  load_tile(t0, F1p, F2p, wp, bm, il, 0);
  for (int jb = 0; jb < CHUNK; jb += 64) {
    load_tile(t1, F1p, F2p, wp, bm, il, jb + 32);
    compute_tile(t0, Rr, g, ones, acc, accS);
    if (jb + 64 < CHUNK) load_tile(t0, F1p, F2p, wp, bm, il, jb + 64);
    compute_tile(t1, Rr, g, ones, acc, accS);
  }

  // partial row sums (all columns of accS equal the rowsum)
#pragma unroll
  for (int rs = 0; rs < 4; ++rs) {
    if (il == 0) {
#pragma unroll
      for (int r = 0; r < 4; ++r)
        psum[(size_t)(ci * NHEADS + hd) * NN + i0 + rs * 16 + g * 4 + r] =
            accS[rs][r];
    }
  }

  // raw accumulator store. C/D: col f = lane&15, row i = 4*(lane>>4)+r
  float* pc = pacc + (size_t)ci * NN * 256;
#pragma unroll
  for (int rs = 0; rs < 4; ++rs)
#pragma unroll
    for (int r = 0; r < 4; ++r)
#pragma unroll
      for (int ft = 0; ft < 4; ++ft)
        pc[(size_t)(i0 + rs * 16 + g * 4 + r) * 256 + hd * 64 + ft * 16 + il] =
            acc[rs][ft][r];
}

// ---------------------------------------------------------------------------
// Kernel 3: combine chunks -> normalize -> ELU -> out = att @ fc_w^T + fc_b
// 256 blocks x 32 rows.
// ---------------------------------------------------------------------------
__global__ __launch_bounds__(256) void k_fc(
    const float* __restrict__ pacc, const float* __restrict__ psum,
    const float* __restrict__ fcw, const float* __restrict__ fcb,
    float* __restrict__ out)
{
  __shared__ float ws[256 * 65];    // fcw transposed: ws[c*65 + o]
  __shared__ float ash[32 * 260];   // combined att rows
  __shared__ float inv[32 * 4];
  const int tid = threadIdx.x;
  const int i0 = blockIdx.x * 32;

  for (int idx = tid; idx < 64 * 256; idx += 256) {
    int o = idx >> 8, c = idx & 255;
    ws[c * 65 + o] = fcw[idx];
  }
  if (tid < 128) {
    int m = tid >> 2, hh = tid & 3;
    float s = 0.f;
#pragma unroll
    for (int ci = 0; ci < NCHUNK; ++ci)
      s += psum[(size_t)(ci * NHEADS + hh) * NN + i0 + m];
    inv[m * 4 + hh] = 1.0f / s;
  }
  __syncthreads();

  for (int idx = tid; idx < 32 * 64; idx += 256) {
    int m = idx >> 6, q = idx & 63;
    int hh = q >> 4;
    size_t off = (size_t)(i0 + m) * 256 + q * 4;
    fx4 v = {};
#pragma unroll
    for (int ci = 0; ci < NCHUNK; ++ci) {
      fx4 a = *(const fx4*)(pacc + (size_t)ci * NN * 256 + off);
      v[0] += a[0]; v[1] += a[1]; v[2] += a[2]; v[3] += a[3];
    }
    float iv = inv[m * 4 + hh];
#pragma unroll
    for (int j = 0; j < 4; ++j) {
      float x = v[j] * iv;
      x = (x > 0.f) ? x : (__builtin_amdgcn_exp2f(x * LOG2E) - 1.0f);  // ELU
      ash[m * 260 + q * 4 + j] = x;
    }
  }
  __syncthreads();

  const int w = tid >> 6, o = tid & 63;
  float acc[8];
#pragma unroll
  for (int m = 0; m < 8; ++m) acc[m] = 0.f;

  for (int c4 = 0; c4 < 64; ++c4) {
    float w0 = ws[(c4 * 4 + 0) * 65 + o];
    float w1 = ws[(c4 * 4 + 1) * 65 + o];
    float w2 = ws[(c4 * 4 + 2) * 65 + o];
    float w3 = ws[(c4 * 4 + 3) * 65 + o];
#pragma unroll
    for (int m = 0; m < 8; ++m) {
      fx4 hv = *(const fx4*)(&ash[(w * 8 + m) * 260 + c4 * 4]);
      acc[m] += hv[0] * w0 + hv[1] * w1 + hv[2] * w2 + hv[3] * w3;
    }
  }
  const float bo = fcb[o];
#pragma unroll
  for (int m = 0; m < 8; ++m)
    out[(size_t)(i0 + w * 8 + m) * 64 + o] = acc[m] + bo;
}

extern "C" void kernel_launch(void* const* d_in, const int* in_sizes, int n_in,
                              void* d_out, int out_size, void* d_ws, size_t ws_size,
                              hipStream_t stream) {
  (void)in_sizes; (void)n_in; (void)out_size; (void)ws_size;
  const float* h   = (const float*)d_in[0];
  const int*   adj = (const int*)d_in[1];
  const float* W   = (const float*)d_in[2];
  const float* a1  = (const float*)d_in[3];
  const float* a2  = (const float*)d_in[4];
  const float* fcw = (const float*)d_in[5];
  const float* fcb = (const float*)d_in[6];
  float* out = (float*)d_out;

  char* base = (char*)d_ws;
  unsigned short* whsw = (unsigned short*)base;            // 4 MiB
  float* R  = (float*)(base + (4u << 20));                 // 128 KiB each
  float* F1 = (float*)(base + (4u << 20) + (128u << 10));
  float* F2 = (float*)(base + (4u << 20) + (256u << 10));
  float* pacc = (float*)(base + (4u << 20) + (512u << 10));          // 32 MiB
  float* psum = (float*)(base + (36u << 20) + (512u << 10));         // 512 KiB

  k_wh<<<dim3(512), dim3(256), 0, stream>>>(h, W, a1, a2, whsw, R, F1, F2);
  k_attn<<<dim3(512), dim3(256), 0, stream>>>(adj, whsw, R, F1, F2, pacc, psum);
  k_fc<<<dim3(256), dim3(256), 0, stream>>>(pacc, psum, fcw, fcb, out);
}

// Round 6
// 231.585 us; speedup vs baseline: 1.0096x; 1.0096x over previous
//
#include <hip/hip_runtime.h>
#include <hip/hip_bf16.h>

#define NN 8192
#define NHEADS 4
#define OUTF 64
#define NCHUNK 2
#define CHUNK 4096
#define ROWS 32
#define LOG2E 1.4426950408889634f

typedef __bf16 bf16x8 __attribute__((ext_vector_type(8)));
typedef float fx4 __attribute__((ext_vector_type(4)));
typedef unsigned short ushort8 __attribute__((ext_vector_type(8)));

// ---------------------------------------------------------------------------
// Kernel 0: adj (int32, 256 MB) -> packed bitmask bm[row][jw] (8 MB).
// Pure streaming; adj is read exactly once chip-wide and never touched again.
// One wave per row; 128 iterations of 64 coalesced dword loads + __ballot.
// ---------------------------------------------------------------------------
__global__ __launch_bounds__(256) void k_bits(
    const int* __restrict__ adj, unsigned* __restrict__ bm)
{
  const int lane = threadIdx.x & 63;
  const int row = blockIdx.x * 4 + (threadIdx.x >> 6);
  const int* ap = adj + (size_t)row * NN;
  unsigned* bp = bm + (size_t)row * (NN / 32);

  for (int it8 = 0; it8 < 16; ++it8) {
    int v[8];
#pragma unroll
    for (int u = 0; u < 8; ++u)
      v[u] = ap[(it8 * 8 + u) * 64 + lane];
#pragma unroll
    for (int u = 0; u < 8; ++u) {
      unsigned long long m = __ballot(v[u] != 0);
      unsigned word = (lane == 1) ? (unsigned)(m >> 32) : (unsigned)m;
      if (lane < 2) bp[(it8 * 8 + u) * 2 + lane] = word;
    }
  }
}

// ---------------------------------------------------------------------------
// Kernel 1: Wh = h @ W[hd] (fp32). Outputs (log2-domain factorization):
//   R [hd][i] = 2^(-0.8*es_i*log2e)   (= exp(-0.8*es))
//   F1[hd][j] = 2^(ed_j*log2e),  F2[hd][j] = 2^(0.2*ed_j*log2e)
//   whsw: bf16 Wh^T pre-swizzled into MFMA-16x16x32 B-fragment order.
// Row-factor E1 cancels in softmax normalization, so it is never computed.
// ---------------------------------------------------------------------------
__global__ __launch_bounds__(256) void k_wh(
    const float* __restrict__ h, const float* __restrict__ W,
    const float* __restrict__ a1, const float* __restrict__ a2,
    unsigned short* __restrict__ whsw, float* __restrict__ R,
    float* __restrict__ F1, float* __restrict__ F2)
{
  __shared__ float ws[64 * 260];  // W[hd] transposed: ws[o*260 + k]
  const int tid = threadIdx.x;
  const int hd = blockIdx.x >> 7;
  const int i0 = (blockIdx.x & 127) << 6;   // 64 rows per block

  const float* Wp = W + hd * (256 * 64);
  for (int idx = tid; idx < 256 * 64; idx += 256) {
    int k = idx >> 6, o = idx & 63;
    ws[o * 260 + k] = Wp[idx];
  }
  __syncthreads();

  const int w = tid >> 6, o = tid & 63;     // wave w: rows ibase..+15, col o
  const int ibase = i0 + w * 16;
  float acc[16];
#pragma unroll
  for (int m = 0; m < 16; ++m) acc[m] = 0.f;

  const float* hp = h + (size_t)ibase * 256;
  for (int k4 = 0; k4 < 64; ++k4) {
    fx4 wv = *(const fx4*)(&ws[o * 260 + k4 * 4]);
#pragma unroll
    for (int m = 0; m < 16; ++m) {
      fx4 hv = *(const fx4*)(hp + m * 256 + k4 * 4);
      acc[m] += hv[0] * wv[0] + hv[1] * wv[1] + hv[2] * wv[2] + hv[3] * wv[3];
    }
  }

  const float a1v = a1[hd * 64 + o], a2v = a2[hd * 64 + o];
#pragma unroll
  for (int m = 0; m < 16; ++m) {
    float s1 = acc[m] * a1v, s2 = acc[m] * a2v;
#pragma unroll
    for (int d = 1; d < 64; d <<= 1) {
      s1 += __shfl_xor(s1, d);
      s2 += __shfl_xor(s2, d);
    }
    if (o == 0) {
      int ix = hd * NN + ibase + m;
      R[ix]  = __builtin_amdgcn_exp2f(-0.8f * s1 * LOG2E);
      F1[ix] = __builtin_amdgcn_exp2f(s2 * LOG2E);
      F2[ix] = __builtin_amdgcn_exp2f(0.2f * s2 * LOG2E);
    }
  }

  // swizzled bf16 store of Wh (rows ibase..+15, col o)
  size_t base = (size_t)hd * 524288 + (size_t)((i0 >> 5) + (w >> 1)) * 2048 +
                (size_t)(o >> 4) * 512;
  int ln0 = (o & 15) + 16 * ((w & 1) * 2);
  ushort8 pk0, pk1;
#pragma unroll
  for (int m = 0; m < 8; ++m) {
    pk0[m] = __builtin_bit_cast(unsigned short, (__bf16)acc[m]);
    pk1[m] = __builtin_bit_cast(unsigned short, (__bf16)acc[m + 8]);
  }
  *(ushort8*)(whsw + base + (size_t)ln0 * 8) = pk0;
  *(ushort8*)(whsw + base + (size_t)(ln0 + 16) * 8) = pk1;
}

// ---------------------------------------------------------------------------
// Kernel 2: masked unnormalized softmax + PV MFMA. NO adj stream here —
// masks come from the precomputed 8 MB bitmask (16 KB/block staged in LDS
// with XOR swizzle; reads conflict-free). whsw/F1/F2/R are L2-resident.
// Grid: 512 blocks = 256 row-tiles (32 rows) x 2 j-chunks (4096);
// ci = bx&1 so even/odd XCDs each keep one 2 MB whsw half hot in L2.
// q = max(F1_j, r_i*F2_j) masked; rowsum via a 5th MFMA (all-ones B).
// ---------------------------------------------------------------------------
struct Tile {
  fx4 f1a, f1b, f2a, f2b;   // F1/F2 slices (per lane group g)
  bf16x8 b0, b1, b2, b3;    // Wh^T B-fragments
  unsigned m[2];            // bitmask words for rowsets 0/1
};

__device__ __forceinline__ void load_tile(Tile& t, const float* F1p,
                                          const float* F2p,
                                          const unsigned short* wp,
                                          const unsigned* bml, int il, int jb)
{
  t.f1a = *(const fx4*)(F1p + jb);
  t.f1b = *(const fx4*)(F1p + jb + 4);
  t.f2a = *(const fx4*)(F2p + jb);
  t.f2b = *(const fx4*)(F2p + jb + 4);
  const unsigned short* wq = wp + (size_t)(jb >> 5) * 2048;
  t.b0 = *(const bf16x8*)(wq);
  t.b1 = *(const bf16x8*)(wq + 512);
  t.b2 = *(const bf16x8*)(wq + 1024);
  t.b3 = *(const bf16x8*)(wq + 1536);
  const int jw = jb >> 5;
  t.m[0] = bml[jw * 32 + (il ^ (jw & 31))];
  t.m[1] = bml[jw * 32 + ((16 + il) ^ (jw & 31))];
}

__device__ __forceinline__ void compute_tile(const Tile& t, const float* Rr,
                                             int g, const bf16x8& ones,
                                             fx4 acc[2][4], fx4* accS)
{
#pragma unroll
  for (int rs = 0; rs < 2; ++rs) {
    unsigned sm = t.m[rs] >> (g * 8);
    float p[8];
#pragma unroll
    for (int e = 0; e < 8; ++e) {
      float f1 = (e < 4) ? t.f1a[e] : t.f1b[e - 4];
      float f2 = (e < 4) ? t.f2a[e] : t.f2b[e - 4];
      float pm = fmaxf(f1, Rr[rs] * f2);   // ∝ exp(leakyrelu(es+ed))
      unsigned keep = (unsigned)(((int)(sm << (31 - e))) >> 31);
      p[e] = __builtin_bit_cast(float,
                 __builtin_bit_cast(unsigned, pm) & keep);
    }
    bf16x8 af;
#pragma unroll
    for (int e = 0; e < 8; ++e) af[e] = (__bf16)p[e];
    acc[rs][0] = __builtin_amdgcn_mfma_f32_16x16x32_bf16(af, t.b0, acc[rs][0], 0, 0, 0);
    acc[rs][1] = __builtin_amdgcn_mfma_f32_16x16x32_bf16(af, t.b1, acc[rs][1], 0, 0, 0);
    acc[rs][2] = __builtin_amdgcn_mfma_f32_16x16x32_bf16(af, t.b2, acc[rs][2], 0, 0, 0);
    acc[rs][3] = __builtin_amdgcn_mfma_f32_16x16x32_bf16(af, t.b3, acc[rs][3], 0, 0, 0);
    accS[rs] = __builtin_amdgcn_mfma_f32_16x16x32_bf16(af, ones, accS[rs], 0, 0, 0);
  }
}

__global__ __launch_bounds__(256) void k_attn(
    const unsigned* __restrict__ bm, const unsigned short* __restrict__ whsw,
    const float* __restrict__ Rg, const float* __restrict__ F1g,
    const float* __restrict__ F2g, float* __restrict__ pacc,
    float* __restrict__ psum)
{
  __shared__ unsigned bml[(CHUNK / 32) * ROWS];   // swizzled [jw][row]: 16 KiB
  const int tid = threadIdx.x;
  const int lane = tid & 63;
  const int hd = tid >> 6;                 // wave = head
  const int bx = blockIdx.x;
  const int ci = bx & 1;                   // chunk; even/odd XCD split
  const int i0 = (bx >> 1) << 5;           // 32 rows
  const int j0 = ci * CHUNK;
  const int il = lane & 15;
  const int g = lane >> 4;

  // ---- stage bitmask slice (16 KB) into LDS, XOR-swizzled ----
  for (int it = 0; it < 16; ++it) {
    int idx = it * 256 + tid;              // 4096 words
    int r = idx >> 7, w = idx & 127;
    unsigned v = bm[(size_t)(i0 + r) * (NN / 32) + (j0 >> 5) + w];
    bml[w * 32 + (r ^ (w & 31))] = v;
  }
  __syncthreads();

  // ---- masked softmax + PV ----
  float Rr[2];
#pragma unroll
  for (int rs = 0; rs < 2; ++rs)
    Rr[rs] = Rg[hd * NN + i0 + rs * 16 + il];
  const float* F1p = F1g + hd * NN + j0 + g * 8;
  const float* F2p = F2g + hd * NN + j0 + g * 8;
  const unsigned short* wp = whsw + (size_t)hd * 524288 +
                             (size_t)(j0 >> 5) * 2048 + (size_t)lane * 8;
  bf16x8 ones;
#pragma unroll
  for (int e = 0; e < 8; ++e) ones[e] = (__bf16)1.0f;

  fx4 acc[2][4] = {};
  fx4 accS[2] = {};

  Tile t0, t1;
  load_tile(t0, F1p, F2p, wp, bml, il, 0);
  for (int jb = 0; jb < CHUNK; jb += 64) {
    load_tile(t1, F1p, F2p, wp, bml, il, jb + 32);
    compute_tile(t0, Rr, g, ones, acc, accS);
    if (jb + 64 < CHUNK) load_tile(t0, F1p, F2p, wp, bml, il, jb + 64);
    compute_tile(t1, Rr, g, ones, acc, accS);
  }

  // partial row sums (all columns of accS equal the rowsum)
#pragma unroll
  for (int rs = 0; rs < 2; ++rs) {
    if (il == 0) {
#pragma unroll
      for (int r = 0; r < 4; ++r)
        psum[(size_t)(ci * NHEADS + hd) * NN + i0 + rs * 16 + g * 4 + r] =
            accS[rs][r];
    }
  }

  // raw accumulator store. C/D: col f = lane&15, row i = 4*(lane>>4)+r
  float* pc = pacc + (size_t)ci * NN * 256;
#pragma unroll
  for (int rs = 0; rs < 2; ++rs)
#pragma unroll
    for (int r = 0; r < 4; ++r)
#pragma unroll
      for (int ft = 0; ft < 4; ++ft)
        pc[(size_t)(i0 + rs * 16 + g * 4 + r) * 256 + hd * 64 + ft * 16 + il] =
            acc[rs][ft][r];
}

// ---------------------------------------------------------------------------
// Kernel 3: combine chunks -> normalize -> ELU -> out = att @ fc_w^T + fc_b
// 256 blocks x 32 rows.
// ---------------------------------------------------------------------------
__global__ __launch_bounds__(256) void k_fc(
    const float* __restrict__ pacc, const float* __restrict__ psum,
    const float* __restrict__ fcw, const float* __restrict__ fcb,
    float* __restrict__ out)
{
  __shared__ float ws[256 * 65];    // fcw transposed: ws[c*65 + o]
  __shared__ float ash[32 * 260];   // combined att rows
  __shared__ float inv[32 * 4];
  const int tid = threadIdx.x;
  const int i0 = blockIdx.x * 32;

  for (int idx = tid; idx < 64 * 256; idx += 256) {
    int o = idx >> 8, c = idx & 255;
    ws[c * 65 + o] = fcw[idx];
  }
  if (tid < 128) {
    int m = tid >> 2, hh = tid & 3;
    float s = 0.f;
#pragma unroll
    for (int ci = 0; ci < NCHUNK; ++ci)
      s += psum[(size_t)(ci * NHEADS + hh) * NN + i0 + m];
    inv[m * 4 + hh] = 1.0f / s;
  }
  __syncthreads();

  for (int idx = tid; idx < 32 * 64; idx += 256) {
    int m = idx >> 6, q = idx & 63;
    int hh = q >> 4;
    size_t off = (size_t)(i0 + m) * 256 + q * 4;
    fx4 v = {};
#pragma unroll
    for (int ci = 0; ci < NCHUNK; ++ci) {
      fx4 a = *(const fx4*)(pacc + (size_t)ci * NN * 256 + off);
      v[0] += a[0]; v[1] += a[1]; v[2] += a[2]; v[3] += a[3];
    }
    float iv = inv[m * 4 + hh];
#pragma unroll
    for (int j = 0; j < 4; ++j) {
      float x = v[j] * iv;
      x = (x > 0.f) ? x : (__builtin_amdgcn_exp2f(x * LOG2E) - 1.0f);  // ELU
      ash[m * 260 + q * 4 + j] = x;
    }
  }
  __syncthreads();

  const int w = tid >> 6, o = tid & 63;
  float acc[8];
#pragma unroll
  for (int m = 0; m < 8; ++m) acc[m] = 0.f;

  for (int c4 = 0; c4 < 64; ++c4) {
    float w0 = ws[(c4 * 4 + 0) * 65 + o];
    float w1 = ws[(c4 * 4 + 1) * 65 + o];
    float w2 = ws[(c4 * 4 + 2) * 65 + o];
    float w3 = ws[(c4 * 4 + 3) * 65 + o];
#pragma unroll
    for (int m = 0; m < 8; ++m) {
      fx4 hv = *(const fx4*)(&ash[(w * 8 + m) * 260 + c4 * 4]);
      acc[m] += hv[0] * w0 + hv[1] * w1 + hv[2] * w2 + hv[3] * w3;
    }
  }
  const float bo = fcb[o];
#pragma unroll
  for (int m = 0; m < 8; ++m)
    out[(size_t)(i0 + w * 8 + m) * 64 + o] = acc[m] + bo;
}

extern "C" void kernel_launch(void* const* d_in, const int* in_sizes, int n_in,
                              void* d_out, int out_size, void* d_ws, size_t ws_size,
                              hipStream_t stream) {
  (void)in_sizes; (void)n_in; (void)out_size; (void)ws_size;
  const float* h   = (const float*)d_in[0];
  const int*   adj = (const int*)d_in[1];
  const float* W   = (const float*)d_in[2];
  const float* a1  = (const float*)d_in[3];
  const float* a2  = (const float*)d_in[4];
  const float* fcw = (const float*)d_in[5];
  const float* fcb = (const float*)d_in[6];
  float* out = (float*)d_out;

  char* base = (char*)d_ws;
  unsigned short* whsw = (unsigned short*)base;            // 4 MiB
  float* R  = (float*)(base + (4u << 20));                 // 128 KiB each
  float* F1 = (float*)(base + (4u << 20) + (128u << 10));
  float* F2 = (float*)(base + (4u << 20) + (256u << 10));
  unsigned* bmask = (unsigned*)(base + (5u << 20));        // 8 MiB
  float* pacc = (float*)(base + (13u << 20));              // 16 MiB
  float* psum = (float*)(base + (29u << 20));              // 256 KiB

  k_bits<<<dim3(2048), dim3(256), 0, stream>>>(adj, bmask);
  k_wh<<<dim3(512), dim3(256), 0, stream>>>(h, W, a1, a2, whsw, R, F1, F2);
  k_attn<<<dim3(512), dim3(256), 0, stream>>>(bmask, whsw, R, F1, F2, pacc, psum);
  k_fc<<<dim3(256), dim3(256), 0, stream>>>(pacc, psum, fcw, fcb, out);
}